// Round 15
// baseline (56.288 us; speedup 1.0000x reference)
//
#include <hip/hip_runtime.h>
#include <hip/hip_bf16.h>

#define N_ 4096
#define D_ 768
#define NCLS 128
#define BM 128
#define BN 128
#define BK 32
#define NSTEP 24  // D_/BK

typedef __bf16 bf16x8 __attribute__((ext_vector_type(8)));
typedef float f32x4 __attribute__((ext_vector_type(4)));
typedef short s16x8 __attribute__((ext_vector_type(8)));

// Normalize: one wave per row, no block sync (2048 blocks x 256 thr).
// Block 0 thread 0 zeroes the reduce accumulators (runs before reduce_kernel).
__global__ __launch_bounds__(256) void normalize_kernel(
    const float* __restrict__ img, const float* __restrict__ txt,
    __hip_bfloat16* __restrict__ img_nb, __hip_bfloat16* __restrict__ txt_nb,
    double* __restrict__ accs, unsigned* __restrict__ cnt) {
  if (blockIdx.x == 0 && threadIdx.x == 0) {
    accs[0] = 0.0;
    accs[1] = 0.0;
    *cnt = 0u;
  }
  int idx = blockIdx.x * 4 + (threadIdx.x >> 6);  // row 0..8191
  int lane = threadIdx.x & 63;
  const float* s;
  __hip_bfloat16* d;
  if (idx < N_) {
    s = img + (size_t)idx * D_;
    d = img_nb + (size_t)idx * D_;
  } else {
    s = txt + (size_t)(idx - N_) * D_;
    d = txt_nb + (size_t)(idx - N_) * D_;
  }
  float4 v0 = ((const float4*)s)[lane];
  float4 v1 = ((const float4*)s)[lane + 64];
  float4 v2 = ((const float4*)s)[lane + 128];
  float ss = v0.x * v0.x + v0.y * v0.y + v0.z * v0.z + v0.w * v0.w +
             v1.x * v1.x + v1.y * v1.y + v1.z * v1.z + v1.w * v1.w +
             v2.x * v2.x + v2.y * v2.y + v2.z * v2.z + v2.w * v2.w;
#pragma unroll
  for (int m = 32; m; m >>= 1) ss += __shfl_xor(ss, m);
  float inv = 1.0f / fmaxf(sqrtf(ss), 1e-8f);
  ushort4 o0, o1, o2;
  o0.x = __bfloat16_as_ushort(__float2bfloat16(v0.x * inv));
  o0.y = __bfloat16_as_ushort(__float2bfloat16(v0.y * inv));
  o0.z = __bfloat16_as_ushort(__float2bfloat16(v0.z * inv));
  o0.w = __bfloat16_as_ushort(__float2bfloat16(v0.w * inv));
  o1.x = __bfloat16_as_ushort(__float2bfloat16(v1.x * inv));
  o1.y = __bfloat16_as_ushort(__float2bfloat16(v1.y * inv));
  o1.z = __bfloat16_as_ushort(__float2bfloat16(v1.z * inv));
  o1.w = __bfloat16_as_ushort(__float2bfloat16(v1.w * inv));
  o2.x = __bfloat16_as_ushort(__float2bfloat16(v2.x * inv));
  o2.y = __bfloat16_as_ushort(__float2bfloat16(v2.y * inv));
  o2.z = __bfloat16_as_ushort(__float2bfloat16(v2.z * inv));
  o2.w = __bfloat16_as_ushort(__float2bfloat16(v2.w * inv));
  ((ushort4*)d)[lane] = o0;
  ((ushort4*)d)[lane + 64] = o1;
  ((ushort4*)d)[lane + 128] = o2;
}

// 128x128-tile bf16 GEMM, BK=32 double-buffered (32KB LDS -> 4 blocks/CU,
// 2x the occupancy of BK=64: cross-block MFMA fills barrier/latency stalls).
// One barrier/step, read-first order, XCD column-stripe block swizzle.
// 4-slot swizzle: slot = gq ^ ((row>>1)&3) at 64B rows -> max 2-way bank
// aliasing (free, m136) on both ds_write_b128 and ds_read_b128.
__global__ __launch_bounds__(256) void gemm_epi_kernel(
    const unsigned short* __restrict__ A, const unsigned short* __restrict__ B,
    const int* __restrict__ labels, float* __restrict__ row_part,
    float* __restrict__ col_part, float* __restrict__ S_part) {
  __shared__ __align__(16) unsigned short As[2][4096];  // [buf][row*4+slot][8]
  __shared__ __align__(16) unsigned short Bs[2][4096];
  __shared__ int labR[BM], labC[BN];
  __shared__ float rbuf[2][BM], cbuf[2][BN];
  __shared__ float sbuf[4];

  // XCD-aware remap (bijective; grid 1024, 1024%8==0)
  const int lin = blockIdx.y * 32 + blockIdx.x;
  const int xcd = lin & 7, idx = lin >> 3;
  const int bx = xcd * 4 + (idx & 3), by = idx >> 2;

  const int tid = threadIdx.x;
  const int lane = tid & 63, wave = tid >> 6;
  const int wr = wave >> 1, wc = wave & 1;
  const int g = lane >> 4, fr = lane & 15;
  const int rowBase = by * BM, colBase = bx * BN;

  if (tid < BM) labR[tid] = labels[rowBase + tid];
  else labC[tid - BM] = labels[colBase + tid - BM];

  // staging: thread t covers 16B chunk gq=t&3 of rows rbase, rbase+64
  const int gq = tid & 3, rbase = tid >> 2;  // rbase 0..63
  const unsigned short* pa = A + (size_t)(rowBase + rbase) * D_ + gq * 8;
  const unsigned short* pb = B + (size_t)(colBase + rbase) * D_ + gq * 8;
  // slot XOR uses (row>>1)&3; rows rbase and rbase+64 share it (64/2 % 4 == 0)
  const int wpos = (rbase * 4 + (gq ^ ((rbase >> 1) & 3))) * 8;  // + j*2048

  f32x4 acc[4][4] = {};

  // fragment slot: row' = wr*64+m*16+fr -> (row'>>1)&3 == (fr>>1)&3 (m*16/2%4==0)
  const int sw = (g ^ ((fr >> 1) & 3)) * 8;

  // prologue: write step 0 into buf0; load step 1 into regs
  s16x8 ra[2], rb[2];
#pragma unroll
  for (int j = 0; j < 2; ++j) {
    ra[j] = *(const s16x8*)(pa + (size_t)(64 * j) * D_);
    rb[j] = *(const s16x8*)(pb + (size_t)(64 * j) * D_);
  }
#pragma unroll
  for (int j = 0; j < 2; ++j) {
    *(s16x8*)&As[0][wpos + j * 2048] = ra[j];
    *(s16x8*)&Bs[0][wpos + j * 2048] = rb[j];
  }
#pragma unroll
  for (int j = 0; j < 2; ++j) {
    ra[j] = *(const s16x8*)(pa + (size_t)(64 * j) * D_ + BK);
    rb[j] = *(const s16x8*)(pb + (size_t)(64 * j) * D_ + BK);
  }
  __syncthreads();  // buf0 resident

  for (int u = 0; u < NSTEP; ++u) {
    const unsigned short* as_ = As[u & 1];
    const unsigned short* bs_ = Bs[u & 1];
    bf16x8 af[4], bf[4];
#pragma unroll
    for (int m = 0; m < 4; ++m)
      af[m] = *(const bf16x8*)&as_[(wr * 64 + m * 16 + fr) * 32 + sw];
#pragma unroll
    for (int n = 0; n < 4; ++n)
      bf[n] = *(const bf16x8*)&bs_[(wc * 64 + n * 16 + fr) * 32 + sw];
    if (u + 1 < NSTEP) {  // write u+1 into other buffer (drains under MFMA)
      unsigned short* aw = As[(u + 1) & 1];
      unsigned short* bw = Bs[(u + 1) & 1];
#pragma unroll
      for (int j = 0; j < 2; ++j) {
        *(s16x8*)&aw[wpos + j * 2048] = ra[j];
        *(s16x8*)&bw[wpos + j * 2048] = rb[j];
      }
    }
#pragma unroll
    for (int m = 0; m < 4; ++m)
#pragma unroll
      for (int n = 0; n < 4; ++n)
        acc[m][n] = __builtin_amdgcn_mfma_f32_16x16x32_bf16(af[m], bf[n], acc[m][n], 0, 0, 0);
    if (u + 2 < NSTEP) {  // global prefetch (staging regs freed by writes above)
      const int k0 = (u + 2) * BK;
#pragma unroll
      for (int j = 0; j < 2; ++j) {
        ra[j] = *(const s16x8*)(pa + (size_t)(64 * j) * D_ + k0);
        rb[j] = *(const s16x8*)(pb + (size_t)(64 * j) * D_ + k0);
      }
    }
    __syncthreads();
  }

  const float scale = 14.285714285714286f;  // 1/0.07
  float sPart = 0.f;
  float colAcc[4] = {0.f, 0.f, 0.f, 0.f};
#pragma unroll
  for (int m = 0; m < 4; ++m) {
    float ra2[4] = {0.f, 0.f, 0.f, 0.f};
#pragma unroll
    for (int n = 0; n < 4; ++n) {
      int col = wc * 64 + n * 16 + fr;
      int lc = labC[col];
#pragma unroll
      for (int r = 0; r < 4; ++r) {
        float v = acc[m][n][r] * scale;
        float e = __expf(v);
        ra2[r] += e;
        colAcc[n] += e;
        int row = wr * 64 + m * 16 + g * 4 + r;
        if (labR[row] == lc) sPart += v;
      }
    }
#pragma unroll
    for (int r = 0; r < 4; ++r) {
      float x = ra2[r];
      x += __shfl_xor(x, 1);
      x += __shfl_xor(x, 2);
      x += __shfl_xor(x, 4);
      x += __shfl_xor(x, 8);
      if (fr == 0) rbuf[wc][wr * 64 + m * 16 + g * 4 + r] = x;
    }
  }
#pragma unroll
  for (int n = 0; n < 4; ++n) {
    float x = colAcc[n];
    x += __shfl_xor(x, 16);
    x += __shfl_xor(x, 32);
    if (g == 0) cbuf[wr][wc * 64 + n * 16 + fr] = x;
  }
  float s = sPart;
#pragma unroll
  for (int m = 32; m; m >>= 1) s += __shfl_xor(s, m);
  if (lane == 0) sbuf[wave] = s;
  __syncthreads();
  if (tid < BM)
    row_part[(size_t)bx * N_ + rowBase + tid] = rbuf[0][tid] + rbuf[1][tid];
  else
    col_part[(size_t)by * N_ + colBase + (tid - BM)] = cbuf[0][tid - BM] + cbuf[1][tid - BM];
  if (tid == 0) S_part[by * 32 + bx] = sbuf[0] + sbuf[1] + sbuf[2] + sbuf[3];
}

// Final reduction merged: per-block hist + partial sums -> device-scope double
// atomics; last-done block writes the scalar loss (accs/cnt zeroed by normalize).
__global__ __launch_bounds__(256) void reduce_kernel(
    const float* __restrict__ row_part, const float* __restrict__ col_part,
    const float* __restrict__ S_part, const int* __restrict__ labels,
    double* __restrict__ accs, unsigned* __restrict__ cnt, float* __restrict__ out) {
  __shared__ int hist[NCLS];
  int tid = threadIdx.x;
  if (tid < NCLS) hist[tid] = 0;
  __syncthreads();
  for (int j = tid; j < N_; j += 256) atomicAdd(&hist[labels[j]], 1);
  __syncthreads();

  int i = blockIdx.x * 256 + tid;  // 0..4095
  float rs = 0.f, cs = 0.f;
#pragma unroll
  for (int b = 0; b < 32; ++b) {
    rs += row_part[(size_t)b * N_ + i];
    cs += col_part[(size_t)b * N_ + i];
  }
  int c = hist[labels[i]];
  double term = (double)c * ((double)logf(rs) + (double)logf(cs));
  double sterm = (i < 1024) ? (double)S_part[i] : 0.0;
#pragma unroll
  for (int m = 32; m; m >>= 1) {
    term += __shfl_xor(term, m);
    sterm += __shfl_xor(sterm, m);
  }
  __shared__ double tbuf[4], sb[4];
  int lane = tid & 63, w = tid >> 6;
  if (lane == 0) { tbuf[w] = term; sb[w] = sterm; }
  __syncthreads();
  if (tid == 0) {
    atomicAdd(&accs[0], tbuf[0] + tbuf[1] + tbuf[2] + tbuf[3]);
    atomicAdd(&accs[1], sb[0] + sb[1] + sb[2] + sb[3]);
    __threadfence();
    unsigned old = atomicAdd(cnt, 1u);
    if (old == 15u) {
      double t = atomicAdd(&accs[0], 0.0);
      double s2 = atomicAdd(&accs[1], 0.0);
      out[0] = (float)((t - 2.0 * s2) / (2.0 * (double)N_));
    }
  }
}

extern "C" void kernel_launch(void* const* d_in, const int* in_sizes, int n_in,
                              void* d_out, int out_size, void* d_ws, size_t ws_size,
                              hipStream_t stream) {
  const float* img = (const float*)d_in[0];
  const float* txt = (const float*)d_in[1];
  const int* labels = (const int*)d_in[2];
  float* out = (float*)d_out;
  char* ws = (char*)d_ws;

  // workspace layout (bytes)
  __hip_bfloat16* img_nb = (__hip_bfloat16*)(ws);             //  6,291,456
  __hip_bfloat16* txt_nb = (__hip_bfloat16*)(ws + 6291456);   //  6,291,456
  float* row_part = (float*)(ws + 12582912);                  //    524,288 (32 x 4096)
  float* col_part = (float*)(ws + 13107200);                  //    524,288
  float* S_part = (float*)(ws + 13631488);                    //      4,096
  double* accs = (double*)(ws + 13635584);                    //  16 (+cnt 4)
  unsigned* cnt = (unsigned*)(ws + 13635600);

  normalize_kernel<<<2 * N_ / 4, 256, 0, stream>>>(img, txt, img_nb, txt_nb, accs, cnt);
  gemm_epi_kernel<<<dim3(32, 32), 256, 0, stream>>>(
      (const unsigned short*)img_nb, (const unsigned short*)txt_nb, labels,
      row_part, col_part, S_part);
  reduce_kernel<<<16, 256, 0, stream>>>(row_part, col_part, S_part, labels, accs, cnt, out);
}

// Round 16
// 53.913 us; speedup vs baseline: 1.0441x; 1.0441x over previous
//
#include <hip/hip_runtime.h>
#include <hip/hip_bf16.h>

#define N_ 4096
#define D_ 768
#define NCLS 128
#define BM 128
#define BN 128
#define BK 64
#define NSTEP 12  // D_/BK

typedef __bf16 bf16x8 __attribute__((ext_vector_type(8)));
typedef float f32x4 __attribute__((ext_vector_type(4)));

#define SBAR() asm volatile("s_barrier" ::: "memory")
#define VMWAIT8() asm volatile("s_waitcnt vmcnt(8)" ::: "memory")
#define LGKM0() asm volatile("s_waitcnt lgkmcnt(0)" ::: "memory")

__device__ __forceinline__ void gload16(const unsigned short* g, unsigned short* l) {
  __builtin_amdgcn_global_load_lds(
      (const __attribute__((address_space(1))) unsigned int*)g,
      (__attribute__((address_space(3))) unsigned int*)l, 16, 0, 0);
}

// Normalize both embedding matrices (blocks [0,N) -> img, [N,2N) -> txt).
// Block 0 zeroes the reduce accumulators (stream order guarantees visibility).
__global__ __launch_bounds__(192) void normalize_kernel(
    const float* __restrict__ img, const float* __restrict__ txt,
    __hip_bfloat16* __restrict__ img_nb, __hip_bfloat16* __restrict__ txt_nb,
    double* __restrict__ accs, unsigned* __restrict__ cnt) {
  int b = blockIdx.x;
  if (b == 0 && threadIdx.x == 0) {
    accs[0] = 0.0;
    accs[1] = 0.0;
    *cnt = 0u;
  }
  const float* s;
  __hip_bfloat16* d;
  if (b < N_) {
    s = img + (size_t)b * D_;
    d = img_nb + (size_t)b * D_;
  } else {
    s = txt + (size_t)(b - N_) * D_;
    d = txt_nb + (size_t)(b - N_) * D_;
  }
  int tid = threadIdx.x;
  float4 v = ((const float4*)s)[tid];
  float ss = v.x * v.x + v.y * v.y + v.z * v.z + v.w * v.w;
#pragma unroll
  for (int m = 32; m; m >>= 1) ss += __shfl_xor(ss, m);
  __shared__ float wsum[3];
  int lane = tid & 63, w = tid >> 6;
  if (lane == 0) wsum[w] = ss;
  __syncthreads();
  float inv = 1.0f / fmaxf(sqrtf(wsum[0] + wsum[1] + wsum[2]), 1e-8f);
  ushort4 o;
  o.x = __bfloat16_as_ushort(__float2bfloat16(v.x * inv));
  o.y = __bfloat16_as_ushort(__float2bfloat16(v.y * inv));
  o.z = __bfloat16_as_ushort(__float2bfloat16(v.z * inv));
  o.w = __bfloat16_as_ushort(__float2bfloat16(v.w * inv));
  ((ushort4*)d)[tid] = o;
}

// 128x128-tile bf16 GEMM. Staging via global_load_lds (no VGPR round-trip, no
// ds_writes): per-lane GLOBAL source pre-swizzled WITHIN each 128B row
// (chunk = (l&7)^(row&7) -- same cache lines, coalescing preserved, m173), so
// the linear LDS dest realizes r7's measured-0-conflict [row][chunk^row&7]
// layout. 2-slot ring, raw s_barrier + counted vmcnt(8): step u+1's 8 loads
// stay in flight across barriers (T4); tail restages a dead slot so the
// vmcnt immediate stays constant. XCD column-stripe block swizzle.
__global__ __launch_bounds__(256) void gemm_epi_kernel(
    const unsigned short* __restrict__ A, const unsigned short* __restrict__ B,
    const int* __restrict__ labels, float* __restrict__ row_part,
    float* __restrict__ col_part, float* __restrict__ S_part) {
  __shared__ __align__(16) unsigned short As[2][8192];  // [slot][row*8+chunk][8]
  __shared__ __align__(16) unsigned short Bs[2][8192];
  __shared__ int labR[BM], labC[BN];
  __shared__ float rbuf[2][BM], cbuf[2][BN];
  __shared__ float sbuf[4];

  // XCD-aware remap (bijective; grid 1024 % 8 == 0)
  const int lin = blockIdx.y * 32 + blockIdx.x;
  const int xcd = lin & 7, idx = lin >> 3;
  const int bx = xcd * 4 + (idx & 3), by = idx >> 2;

  const int tid = threadIdx.x;
  const int lane = tid & 63, wave = tid >> 6;
  const int wr = wave >> 1, wc = wave & 1;
  const int g = lane >> 4, fr = lane & 15;
  const int rowBase = by * BM, colBase = bx * BN;

  if (tid < BM) labR[tid] = labels[rowBase + tid];
  else labC[tid - BM] = labels[colBase + tid - BM];
  __syncthreads();  // labels visible (full drain once, before any gload issue)

  // staging: wave w, issue j covers rows j*32 + w*8 .. +8; lane l -> row r0=l>>3,
  // swizzled chunk (l&7)^(r0&7). LDS dest linear: &As[slot][(j*32+w*8)*64] + l*16B.
  const int r0 = lane >> 3;
  const int cswz = (lane & 7) ^ (r0 & 7);
  const unsigned short* pa = A + (size_t)(rowBase + wave * 8 + r0) * D_ + cswz * 8;
  const unsigned short* pb = B + (size_t)(colBase + wave * 8 + r0) * D_ + cswz * 8;
  const int dbase = wave * 8 * 64;  // ushort idx; + j*32*64

  // prologue: issue step 0 into slot 0 (8 loads in flight)
#pragma unroll
  for (int j = 0; j < 4; ++j) {
    gload16(pa + (size_t)(32 * j) * D_, &As[0][dbase + j * 2048]);
    gload16(pb + (size_t)(32 * j) * D_, &Bs[0][dbase + j * 2048]);
  }

  f32x4 acc[4][4] = {};

  for (int u = 0; u < NSTEP; ++u) {
    SBAR();  // all waves done reading the slot about to be overwritten
    {
      const int su = (u + 1 < NSTEP) ? u + 1 : u;  // tail: restage dead slot
      const size_t kk = (size_t)su * BK;
      const int sl = (u + 1) & 1;
#pragma unroll
      for (int j = 0; j < 4; ++j) {
        gload16(pa + (size_t)(32 * j) * D_ + kk, &As[sl][dbase + j * 2048]);
        gload16(pb + (size_t)(32 * j) * D_ + kk, &Bs[sl][dbase + j * 2048]);
      }
    }
    VMWAIT8();  // my step-u loads landed; step-u+1's 8 stay in flight
    SBAR();     // every wave's step-u loads landed: slot u&1 fully valid
    const unsigned short* as_ = As[u & 1];
    const unsigned short* bs_ = Bs[u & 1];
#pragma unroll
    for (int ks = 0; ks < 2; ++ks) {
      const int sw = (ks * 4 + g) ^ (fr & 7);  // chunk, swizzled; row&7 == fr&7
      bf16x8 af[4], bf[4];
#pragma unroll
      for (int m = 0; m < 4; ++m)
        af[m] = *(const bf16x8*)&as_[((wr * 64 + m * 16 + fr) * 8 + sw) * 8];
#pragma unroll
      for (int n = 0; n < 4; ++n)
        bf[n] = *(const bf16x8*)&bs_[((wc * 64 + n * 16 + fr) * 8 + sw) * 8];
#pragma unroll
      for (int m = 0; m < 4; ++m)
#pragma unroll
        for (int n = 0; n < 4; ++n)
          acc[m][n] = __builtin_amdgcn_mfma_f32_16x16x32_bf16(af[m], bf[n], acc[m][n], 0, 0, 0);
    }
    LGKM0();  // my ds_reads drained before signaling the next top barrier
  }
  __syncthreads();  // full drain before epilogue LDS reuse

  const float scale = 14.285714285714286f;  // 1/0.07
  float sPart = 0.f;
  float colAcc[4] = {0.f, 0.f, 0.f, 0.f};
#pragma unroll
  for (int m = 0; m < 4; ++m) {
    float ra2[4] = {0.f, 0.f, 0.f, 0.f};
#pragma unroll
    for (int n = 0; n < 4; ++n) {
      int col = wc * 64 + n * 16 + fr;
      int lc = labC[col];
#pragma unroll
      for (int r = 0; r < 4; ++r) {
        float v = acc[m][n][r] * scale;
        float e = __expf(v);
        ra2[r] += e;
        colAcc[n] += e;
        int row = wr * 64 + m * 16 + g * 4 + r;
        if (labR[row] == lc) sPart += v;
      }
    }
#pragma unroll
    for (int r = 0; r < 4; ++r) {
      float x = ra2[r];
      x += __shfl_xor(x, 1);
      x += __shfl_xor(x, 2);
      x += __shfl_xor(x, 4);
      x += __shfl_xor(x, 8);
      if (fr == 0) rbuf[wc][wr * 64 + m * 16 + g * 4 + r] = x;
    }
  }
#pragma unroll
  for (int n = 0; n < 4; ++n) {
    float x = colAcc[n];
    x += __shfl_xor(x, 16);
    x += __shfl_xor(x, 32);
    if (g == 0) cbuf[wr][wc * 64 + n * 16 + fr] = x;
  }
  float s = sPart;
#pragma unroll
  for (int m = 32; m; m >>= 1) s += __shfl_xor(s, m);
  if (lane == 0) sbuf[wave] = s;
  __syncthreads();
  if (tid < BM)
    row_part[(size_t)bx * N_ + rowBase + tid] = rbuf[0][tid] + rbuf[1][tid];
  else
    col_part[(size_t)by * N_ + colBase + (tid - BM)] = cbuf[0][tid - BM] + cbuf[1][tid - BM];
  if (tid == 0) S_part[by * 32 + bx] = sbuf[0] + sbuf[1] + sbuf[2] + sbuf[3];
}

// Merged final reduction: per-block hist + partials -> device-scope double
// atomics; last-done block writes the scalar loss.
__global__ __launch_bounds__(256) void reduce_kernel(
    const float* __restrict__ row_part, const float* __restrict__ col_part,
    const float* __restrict__ S_part, const int* __restrict__ labels,
    double* __restrict__ accs, unsigned* __restrict__ cnt, float* __restrict__ out) {
  __shared__ int hist[NCLS];
  int tid = threadIdx.x;
  if (tid < NCLS) hist[tid] = 0;
  __syncthreads();
  for (int j = tid; j < N_; j += 256) atomicAdd(&hist[labels[j]], 1);
  __syncthreads();

  int i = blockIdx.x * 256 + tid;  // 0..4095
  float rs = 0.f, cs = 0.f;
#pragma unroll
  for (int b = 0; b < 32; ++b) {
    rs += row_part[(size_t)b * N_ + i];
    cs += col_part[(size_t)b * N_ + i];
  }
  int c = hist[labels[i]];
  double term = (double)c * ((double)logf(rs) + (double)logf(cs));
  double sterm = (i < 1024) ? (double)S_part[i] : 0.0;
#pragma unroll
  for (int m = 32; m; m >>= 1) {
    term += __shfl_xor(term, m);
    sterm += __shfl_xor(sterm, m);
  }
  __shared__ double tbuf[4], sb[4];
  int lane = tid & 63, w = tid >> 6;
  if (lane == 0) { tbuf[w] = term; sb[w] = sterm; }
  __syncthreads();
  if (tid == 0) {
    atomicAdd(&accs[0], tbuf[0] + tbuf[1] + tbuf[2] + tbuf[3]);
    atomicAdd(&accs[1], sb[0] + sb[1] + sb[2] + sb[3]);
    __threadfence();
    unsigned old = atomicAdd(cnt, 1u);
    if (old == 15u) {
      double t = atomicAdd(&accs[0], 0.0);
      double s2 = atomicAdd(&accs[1], 0.0);
      out[0] = (float)((t - 2.0 * s2) / (2.0 * (double)N_));
    }
  }
}

extern "C" void kernel_launch(void* const* d_in, const int* in_sizes, int n_in,
                              void* d_out, int out_size, void* d_ws, size_t ws_size,
                              hipStream_t stream) {
  const float* img = (const float*)d_in[0];
  const float* txt = (const float*)d_in[1];
  const int* labels = (const int*)d_in[2];
  float* out = (float*)d_out;
  char* ws = (char*)d_ws;

  // workspace layout (bytes)
  __hip_bfloat16* img_nb = (__hip_bfloat16*)(ws);             //  6,291,456
  __hip_bfloat16* txt_nb = (__hip_bfloat16*)(ws + 6291456);   //  6,291,456
  float* row_part = (float*)(ws + 12582912);                  //    524,288 (32 x 4096)
  float* col_part = (float*)(ws + 13107200);                  //    524,288
  float* S_part = (float*)(ws + 13631488);                    //      4,096
  double* accs = (double*)(ws + 13635584);                    //  16 (+cnt 4)
  unsigned* cnt = (unsigned*)(ws + 13635600);

  normalize_kernel<<<2 * N_, 192, 0, stream>>>(img, txt, img_nb, txt_nb, accs, cnt);
  gemm_epi_kernel<<<dim3(32, 32), 256, 0, stream>>>(
      (const unsigned short*)img_nb, (const unsigned short*)txt_nb, labels,
      row_part, col_part, S_part);
  reduce_kernel<<<16, 256, 0, stream>>>(row_part, col_part, S_part, labels, accs, cnt, out);
}